// Round 5
// baseline (502.799 us; speedup 1.0000x reference)
//
#include <hip/hip_runtime.h>

#define N_DATA   128
#define SEG_LEN  131072
#define NPROD    (SEG_LEN - 1)
#define N_MAT    8
#define N_MATP   8
#define N_PROCP  5
#define RGAS     8.314f

#define TPB      256
#define RUNS     8                    // runs of 4 elements per lane
#define EPT      (RUNS * 4)           // 32 elements per lane
#define WCHUNK   (64 * EPT)           // 2048 elements per wave
#define WPR      (SEG_LEN / WCHUNK)   // 64 wave-slots per row (one u64 mask!)
#define NWAVE    (N_DATA * WPR)       // 8192 waves total (~1 residency generation)
#define NBLK     (NWAVE / (TPB / 64)) // 2048 blocks

typedef float nt4 __attribute__((ext_vector_type(4)));  // native vec for nontemporal builtin

// sigma_ss = (base_num*u*Lg + Sigma0*cbd) / (Lg*(u+cbd)),  u = R*Lg + 1e-9
__device__ __forceinline__ float stress_s(float t,
    float alpha1, float L0, float G200, float Sigma0, float A0,
    float inv_tau, float cbd, float base_num, float R) {
  float Lg  = G200 * __expf(alpha1 * __logf(t * (1.0f / 200.0f) + 0.001f)) + L0;
  float u   = R * Lg + 1e-9f;
  float num = base_num * u * Lg + Sigma0 * cbd;
  float den = Lg * (u + cbd);
  float sigma_ss = num * __builtin_amdgcn_rcpf(den);
  return sigma_ss + A0 * __expf(-t * inv_tau);
}

// K0: re-arm the per-row ready masks (workspace is re-poisoned between
// iterations; poison bits could fake "ready"). Values need no init: a value
// is only read after its mask bit was set THIS launch, and the bit is set
// only after the value store (release). Kernel => graph-capture-safe.
__global__ __launch_bounds__(128) void k0_init(unsigned long long* __restrict__ mask) {
  mask[threadIdx.x] = 0ull;
}

// Single-pass scan, WAVE-grained, zero barriers, zero LDS, dense memory ops,
// CHEAP sync. Wave w owns elements [w*2048, w*2048+2048). Lane i owns 8 runs
// of 4 at wavebase + r*256 + i*4, so every dwordx4 load/store is lane-dense
// (1024B per instruction -- round-2's strided layout cost +53MB HBM writes).
//
// Sync protocol (round-4 lesson: per-lane scattered atomic spin loads from
// thousands of waves saturate the coherence fabric and capped EVERYTHING at
// ~2 TB/s):
//   publish: lane0 stores wave total (relaxed, agent) to val[row*64+s],
//            then atomic_or(mask[row], 1<<s, RELEASE) -- one u64 per row.
//   wait:    spin on ONE wave-uniform 8B load of mask[row] per retry
//            (64 lanes same address = single transaction), s_sleep between.
//   gather:  after acquire fence, ONE non-spinning pass: lane l<s loads
//            val[row*64+l], butterfly-reduce -> row offset.
// Predecessors have lower blockIdx => in-order dispatch => resident or
// retired (rocPRIM single-pass-scan forward-progress assumption).
//
// CORRECTNESS (round-3 lesson): every __shfl executes in FULL exec; only
// loads/selects may sit in divergent code.
__global__ __launch_bounds__(TPB) void k_scan(
    const float* __restrict__ x,
    const float* __restrict__ pc, const float* __restrict__ raw,
    const float* __restrict__ lb, const float* __restrict__ ub,
    const float* __restrict__ sc, const int* __restrict__ mat_idx,
    unsigned long long* __restrict__ mask, float* __restrict__ val,
    float* __restrict__ out) {
  int tid  = threadIdx.x;
  int lane = tid & 63;
  int w    = blockIdx.x * (TPB >> 6) + (tid >> 6);     // global wave id
  int row  = __builtin_amdgcn_readfirstlane(w / WPR);  // wave-uniform -> SGPR
  int s    = __builtin_amdgcn_readfirstlane(w & (WPR - 1));

  // issue x loads immediately (fly during param compute); lane-contiguous
  long rowbase = (long)row * SEG_LEN;
  int  gb0 = s * WCHUNK;                               // row-local wave base
  const float* xp = x + rowbase + gb0 + lane * 4;
  float4 v[RUNS];
#pragma unroll
  for (int r = 0; r < RUNS; r++) v[r] = *(const float4*)(xp + r * 256);
  float xe = 0.0f;                                     // cross-wave edge
  if (lane == 63 && gb0 + WCHUNK < SEG_LEN) xe = x[rowbase + gb0 + WCHUNK];

  // param transform: lanes 0..12 compute one sigmoid each; broadcast by shfl
  float pvl = 0.0f;
  if (lane < 13) {
    int idx = (lane < 5) ? (N_MAT * N_MATP + row * N_PROCP + lane)
                         : (mat_idx[row] * N_MATP + (lane - 5));
    float sg = 1.0f / (1.0f + __expf(-raw[idx]));
    pvl = sg * (ub[idx] - lb[idx]) + lb[idx];
  }
  float SigmaC = __shfl(pvl, 0),  K0   = __shfl(pvl, 1), alpha1 = __shfl(pvl, 2);
  float L0     = __shfl(pvl, 3),  G200 = __shfl(pvl, 4);
  float Sigma0 = __shfl(pvl, 5),  BetaD = __shfl(pvl, 6), Ea = __shfl(pvl, 7);
  float Mfda   = __shfl(pvl, 8),  Di   = __shfl(pvl, 9);
  float A0     = __shfl(pvl, 10), B0   = __shfl(pvl, 11), l0 = __shfl(pvl, 12);

  float R = pc[row * 4 + 0], T = pc[row * 4 + 1], P = pc[row * 4 + 2];
  float cbd      = BetaD * Di * __expf(-Ea / (RGAS * T));
  float base_num = SigmaC - Mfda * P;
  float inv_tau  = 1.0f / (B0 * l0 + 1e-9f);
  float x_min = sc[0], x_sc = sc[1] - sc[0];
  float y_min = sc[2], inv_yr = 1.0f / (sc[3] - sc[2]);

  // x -> t
  float t[RUNS][4];
#pragma unroll
  for (int r = 0; r < RUNS; r++) {
    t[r][0] = v[r].x * x_sc + x_min;
    t[r][1] = v[r].y * x_sc + x_min;
    t[r][2] = v[r].z * x_sc + x_min;
    t[r][3] = v[r].w * x_sc + x_min;
  }

  // t_next for each run's last element: ALL shuffles full-exec, then select.
  float nx[RUNS];
  {
    float dsh[RUNS], bc[RUNS];
#pragma unroll
    for (int r = 0; r < RUNS; r++) dsh[r] = __shfl_down(t[r][0], 1);
#pragma unroll
    for (int r = 0; r < RUNS - 1; r++) bc[r] = __shfl(t[r + 1][0], 0);
    bc[RUNS - 1] = xe * x_sc + x_min;   // valid on lane 63 (only user)
    bool last = (lane == 63);
#pragma unroll
    for (int r = 0; r < RUNS; r++) nx[r] = last ? bc[r] : dsh[r];
  }

  // products, in place over t (t[r][k] dead after p[r][k] computed)
  int glb = gb0 + lane * 4;   // row-local index of run-0 element 0
  float rs[RUNS];
#pragma unroll
  for (int r = 0; r < RUNS; r++) {
    float acc = 0.0f;
#pragma unroll
    for (int k = 0; k < 4; k++) {
      float tn = (k < 3) ? t[r][k + 1] : nx[r];
      float pp = 0.0f;
      if (glb + r * 256 + k < NPROD) {
        float ss = stress_s(t[r][k], alpha1, L0, G200, Sigma0, A0,
                            inv_tau, cbd, base_num, R);
        pp = ss * (tn - t[r][k]);
      }
      acc += pp;
      t[r][k] = pp;           // t now holds products
    }
    rs[r] = acc;
  }

  // wave total via butterfly -> publish ASAP (before scan work)
  float tot = rs[0] + rs[1] + rs[2] + rs[3] + rs[4] + rs[5] + rs[6] + rs[7];
#pragma unroll
  for (int d = 1; d < 64; d <<= 1) tot += __shfl_xor(tot, d);
  if (lane == 0) {
    __hip_atomic_store(val + ((row << 6) + s), tot,
                       __ATOMIC_RELAXED, __HIP_MEMORY_SCOPE_AGENT);
    __hip_atomic_fetch_or(mask + row, 1ull << s,
                          __ATOMIC_RELEASE, __HIP_MEMORY_SCOPE_AGENT);
  }

  // 8 chained inclusive wave-scans -> per-run exclusive prefixes.
  // This VALU/DS work overlaps predecessors' publish latency.
  float e[RUNS];
  float carry = 0.0f;
#pragma unroll
  for (int r = 0; r < RUNS; r++) {
    float inc = rs[r];
#pragma unroll
    for (int d = 1; d < 64; d <<= 1) {
      float nn = __shfl_up(inc, d);
      if (lane >= d) inc += nn;
    }
    e[r] = carry + inc - rs[r];
    carry += __shfl(inc, 63);
  }

  // pre-scale store values in place (row offset folded in after the wait)
#pragma unroll
  for (int r = 0; r < RUNS; r++) {
    float c0 = K0 + e[r] - y_min;
    float c1 = c0 + t[r][0];
    float c2 = c1 + t[r][1];
    float c3 = c2 + t[r][2];
    t[r][0] = c0 * inv_yr; t[r][1] = c1 * inv_yr;
    t[r][2] = c2 * inv_yr; t[r][3] = c3 * inv_yr;
  }

  // cheap wait: wave-uniform single-transaction spin on the row mask
  float choff = 0.0f;
  if (s > 0) {                                   // wave-uniform branch
    unsigned long long need = (1ull << s) - 1ull;
    const unsigned long long* mp = mask + row;
    unsigned long long m = __hip_atomic_load(mp, __ATOMIC_RELAXED,
                                             __HIP_MEMORY_SCOPE_AGENT);
    while ((m & need) != need) {
      __builtin_amdgcn_s_sleep(2);
      m = __hip_atomic_load(mp, __ATOMIC_RELAXED, __HIP_MEMORY_SCOPE_AGENT);
    }
    __builtin_amdgcn_fence(__ATOMIC_ACQUIRE, "agent");
    // one non-spinning gather: lane l < s loads predecessor l's total
    float vv = 0.0f;
    if (lane < s)
      vv = __hip_atomic_load(val + ((row << 6) + lane),
                             __ATOMIC_RELAXED, __HIP_MEMORY_SCOPE_AGENT);
#pragma unroll
    for (int d = 32; d > 0; d >>= 1) vv += __shfl_down(vv, d);   // full exec
    choff = __shfl(vv, 0) * inv_yr;            // already output-scaled
  }

  // dense nontemporal stores: lane i at base + i*16B, 1024B per instruction
  float* ob = out + rowbase + gb0 + lane * 4;
#pragma unroll
  for (int r = 0; r < RUNS; r++) {
    nt4 o;
    o.x = t[r][0] + choff; o.y = t[r][1] + choff;
    o.z = t[r][2] + choff; o.w = t[r][3] + choff;
    __builtin_nontemporal_store(o, (nt4*)(ob + r * 256));  // out never re-read
  }
}

extern "C" void kernel_launch(void* const* d_in, const int* in_sizes, int n_in,
                              void* d_out, int out_size, void* d_ws, size_t ws_size,
                              hipStream_t stream) {
  const float* x_scaled  = (const float*)d_in[0];
  const float* process_c = (const float*)d_in[1];
  const float* raw       = (const float*)d_in[2];
  const float* lb        = (const float*)d_in[3];
  const float* ub        = (const float*)d_in[4];
  const float* sc        = (const float*)d_in[5];
  // d_in[6] = fit_index (unused by the reference computation)
  const int*   mat_idx   = (const int*)d_in[7];
  float* out = (float*)d_out;
  unsigned long long* mask = (unsigned long long*)d_ws;    // 128 u64 ready masks
  float* val = (float*)(mask + N_DATA);                    // 8192 wave totals

  k0_init<<<1, N_DATA, 0, stream>>>(mask);
  k_scan<<<NBLK, TPB, 0, stream>>>(
      x_scaled, process_c, raw, lb, ub, sc, mat_idx, mask, val, out);
}

// Round 6
// 173.378 us; speedup vs baseline: 2.9000x; 2.9000x over previous
//
#include <hip/hip_runtime.h>

#define N_DATA   128
#define SEG_LEN  131072
#define NPROD    (SEG_LEN - 1)
#define N_MAT    8
#define N_MATP   8
#define N_PROCP  5
#define RGAS     8.314f

#define TPB      256
#define RUNS     8                    // runs of 4 elements per lane
#define EPT      (RUNS * 4)           // 32 elements per lane
#define WCHUNK   (64 * EPT)           // 2048 elements per wave
#define WPR      (SEG_LEN / WCHUNK)   // 64 wave-slots per row -> 1 poll slot/lane
#define NWAVE    (N_DATA * WPR)       // 8192 waves == 256 CU x 32 waves/CU:
                                      // ONE residency generation, all publishes
                                      // land while all consumers are live
#define NBLK     (NWAVE / (TPB / 64)) // 2048 blocks

typedef float nt4 __attribute__((ext_vector_type(4)));  // native vec for nontemporal builtin

// sigma_ss = (base_num*u*Lg + Sigma0*cbd) / (Lg*(u+cbd)),  u = R*Lg + 1e-9
__device__ __forceinline__ float stress_s(float t,
    float alpha1, float L0, float G200, float Sigma0, float A0,
    float inv_tau, float cbd, float base_num, float R) {
  float Lg  = G200 * __expf(alpha1 * __logf(t * (1.0f / 200.0f) + 0.001f)) + L0;
  float u   = R * Lg + 1e-9f;
  float num = base_num * u * Lg + Sigma0 * cbd;
  float den = Lg * (u + cbd);
  float sigma_ss = num * __builtin_amdgcn_rcpf(den);
  return sigma_ss + A0 * __expf(-t * inv_tau);
}

// K0: re-arm the packed {ready|value} words (workspace is re-poisoned between
// iterations; poison bits could fake "ready"). Kernel => graph-capture-safe.
__global__ __launch_bounds__(TPB) void k0_init(unsigned long long* __restrict__ cs) {
  cs[blockIdx.x * TPB + threadIdx.x] = 0ull;
}

// Single-pass scan, WAVE-grained, zero barriers, zero LDS, dense memory ops,
// FENCE-FREE sync. Wave w owns elements [w*2048, w*2048+2048). Lane i owns
// 8 runs of 4 at wavebase + r*256 + i*4 => every dwordx4 load/store is
// lane-dense (1024B per instruction; round-2's strided layout cost +53MB of
// partial-line write amplification).
//
// Sync protocol -- ROUND-5 LESSON baked in: flag and value live in ONE u64
// ({ready<<32 | float_bits}) so relaxed agent-scope atomics suffice. Any
// agent-scope release/acquire fence on gfx950 compiles to a whole-L2
// writeback/invalidate (per-XCD L2s are non-coherent) and cost 7x wall time.
//   publish: lane0 relaxed-stores the packed word to cs[w] right after the
//            wave-total reduce, BEFORE the scan work.
//   wait:    lane l < s polls cs[row*64+l] (exactly one slot per lane),
//            s_sleep(1) between retries; then full-exec butterfly reduce.
// Predecessors have lower blockIdx => in-order dispatch => already resident
// (one-generation sizing) or retired (rocPRIM forward-progress assumption).
//
// CORRECTNESS (round-3 lesson): every __shfl executes in FULL exec; only
// loads/selects may sit in divergent code.
__global__ __launch_bounds__(TPB) void k_scan(
    const float* __restrict__ x,
    const float* __restrict__ pc, const float* __restrict__ raw,
    const float* __restrict__ lb, const float* __restrict__ ub,
    const float* __restrict__ sc, const int* __restrict__ mat_idx,
    unsigned long long* __restrict__ cs,
    float* __restrict__ out) {
  int tid  = threadIdx.x;
  int lane = tid & 63;
  int w    = blockIdx.x * (TPB >> 6) + (tid >> 6);     // global wave id
  int row  = __builtin_amdgcn_readfirstlane(w >> 6);   // wave-uniform -> SGPR
  int s    = __builtin_amdgcn_readfirstlane(w & (WPR - 1));

  // issue x loads immediately (fly during param compute); lane-contiguous
  long rowbase = (long)row * SEG_LEN;
  int  gb0 = s * WCHUNK;                               // row-local wave base
  const float* xp = x + rowbase + gb0 + lane * 4;
  float4 v[RUNS];
#pragma unroll
  for (int r = 0; r < RUNS; r++) v[r] = *(const float4*)(xp + r * 256);
  float xe = 0.0f;                                     // cross-wave edge
  if (lane == 63 && gb0 + WCHUNK < SEG_LEN) xe = x[rowbase + gb0 + WCHUNK];

  // param transform: lanes 0..12 compute one sigmoid each; broadcast by shfl
  float pvl = 0.0f;
  if (lane < 13) {
    int idx = (lane < 5) ? (N_MAT * N_MATP + row * N_PROCP + lane)
                         : (mat_idx[row] * N_MATP + (lane - 5));
    float sg = 1.0f / (1.0f + __expf(-raw[idx]));
    pvl = sg * (ub[idx] - lb[idx]) + lb[idx];
  }
  float SigmaC = __shfl(pvl, 0),  K0   = __shfl(pvl, 1), alpha1 = __shfl(pvl, 2);
  float L0     = __shfl(pvl, 3),  G200 = __shfl(pvl, 4);
  float Sigma0 = __shfl(pvl, 5),  BetaD = __shfl(pvl, 6), Ea = __shfl(pvl, 7);
  float Mfda   = __shfl(pvl, 8),  Di   = __shfl(pvl, 9);
  float A0     = __shfl(pvl, 10), B0   = __shfl(pvl, 11), l0 = __shfl(pvl, 12);

  float R = pc[row * 4 + 0], T = pc[row * 4 + 1], P = pc[row * 4 + 2];
  float cbd      = BetaD * Di * __expf(-Ea / (RGAS * T));
  float base_num = SigmaC - Mfda * P;
  float inv_tau  = 1.0f / (B0 * l0 + 1e-9f);
  float x_min = sc[0], x_sc = sc[1] - sc[0];
  float y_min = sc[2], inv_yr = 1.0f / (sc[3] - sc[2]);

  // x -> t
  float t[RUNS][4];
#pragma unroll
  for (int r = 0; r < RUNS; r++) {
    t[r][0] = v[r].x * x_sc + x_min;
    t[r][1] = v[r].y * x_sc + x_min;
    t[r][2] = v[r].z * x_sc + x_min;
    t[r][3] = v[r].w * x_sc + x_min;
  }

  // t_next for each run's last element: ALL shuffles full-exec, then select.
  float nx[RUNS];
  {
    float dsh[RUNS], bc[RUNS];
#pragma unroll
    for (int r = 0; r < RUNS; r++) dsh[r] = __shfl_down(t[r][0], 1);
#pragma unroll
    for (int r = 0; r < RUNS - 1; r++) bc[r] = __shfl(t[r + 1][0], 0);
    bc[RUNS - 1] = xe * x_sc + x_min;   // valid on lane 63 (only user)
    bool last = (lane == 63);
#pragma unroll
    for (int r = 0; r < RUNS; r++) nx[r] = last ? bc[r] : dsh[r];
  }

  // products, in place over t (t[r][k] dead after its product is computed)
  int glb = gb0 + lane * 4;   // row-local index of run-0 element 0
  float rs[RUNS];
#pragma unroll
  for (int r = 0; r < RUNS; r++) {
    float acc = 0.0f;
#pragma unroll
    for (int k = 0; k < 4; k++) {
      float tn = (k < 3) ? t[r][k + 1] : nx[r];
      float pp = 0.0f;
      if (glb + r * 256 + k < NPROD) {
        float ss = stress_s(t[r][k], alpha1, L0, G200, Sigma0, A0,
                            inv_tau, cbd, base_num, R);
        pp = ss * (tn - t[r][k]);
      }
      acc += pp;
      t[r][k] = pp;           // t now holds products
    }
    rs[r] = acc;
  }

  // wave total via butterfly -> publish ASAP (before scan work)
  float tot = rs[0] + rs[1] + rs[2] + rs[3] + rs[4] + rs[5] + rs[6] + rs[7];
#pragma unroll
  for (int d = 1; d < 64; d <<= 1) tot += __shfl_xor(tot, d);
  if (lane == 0) {
    unsigned long long u = (1ull << 32) |
        (unsigned long long)__float_as_uint(tot);
    __hip_atomic_store(cs + w, u, __ATOMIC_RELAXED, __HIP_MEMORY_SCOPE_AGENT);
  }

  // 8 chained inclusive wave-scans -> per-run exclusive prefixes.
  // This VALU/DS work overlaps predecessors' publish latency.
  float e[RUNS];
  float carry = 0.0f;
#pragma unroll
  for (int r = 0; r < RUNS; r++) {
    float inc = rs[r];
#pragma unroll
    for (int d = 1; d < 64; d <<= 1) {
      float nn = __shfl_up(inc, d);
      if (lane >= d) inc += nn;
    }
    e[r] = carry + inc - rs[r];
    carry += __shfl(inc, 63);
  }

  // pre-scale store values in place (row offset folded in after the wait)
#pragma unroll
  for (int r = 0; r < RUNS; r++) {
    float c0 = K0 + e[r] - y_min;
    float c1 = c0 + t[r][0];
    float c2 = c1 + t[r][1];
    float c3 = c2 + t[r][2];
    t[r][0] = c0 * inv_yr; t[r][1] = c1 * inv_yr;
    t[r][2] = c2 * inv_yr; t[r][3] = c3 * inv_yr;
  }

  // wait + gather: lane l < s polls exactly one packed slot (WPR=64).
  // Divergent region contains ONLY loads; shuffles follow in full exec.
  float vv = 0.0f;
  if (lane < s) {
    const unsigned long long* p = cs + ((row << 6) + lane);
    unsigned long long u = __hip_atomic_load(p, __ATOMIC_RELAXED,
                                             __HIP_MEMORY_SCOPE_AGENT);
    while (!(unsigned)(u >> 32)) {
      __builtin_amdgcn_s_sleep(1);
      u = __hip_atomic_load(p, __ATOMIC_RELAXED, __HIP_MEMORY_SCOPE_AGENT);
    }
    vv = __uint_as_float((unsigned)u);
  }
#pragma unroll
  for (int d = 32; d > 0; d >>= 1) vv += __shfl_down(vv, d);   // full exec
  float choff = __shfl(vv, 0) * inv_yr;        // already output-scaled

  // dense nontemporal stores: lane i at base + i*16B, 1024B per instruction
  float* ob = out + rowbase + gb0 + lane * 4;
#pragma unroll
  for (int r = 0; r < RUNS; r++) {
    nt4 o;
    o.x = t[r][0] + choff; o.y = t[r][1] + choff;
    o.z = t[r][2] + choff; o.w = t[r][3] + choff;
    __builtin_nontemporal_store(o, (nt4*)(ob + r * 256));  // out never re-read
  }
}

extern "C" void kernel_launch(void* const* d_in, const int* in_sizes, int n_in,
                              void* d_out, int out_size, void* d_ws, size_t ws_size,
                              hipStream_t stream) {
  const float* x_scaled  = (const float*)d_in[0];
  const float* process_c = (const float*)d_in[1];
  const float* raw       = (const float*)d_in[2];
  const float* lb        = (const float*)d_in[3];
  const float* ub        = (const float*)d_in[4];
  const float* sc        = (const float*)d_in[5];
  // d_in[6] = fit_index (unused by the reference computation)
  const int*   mat_idx   = (const int*)d_in[7];
  float* out = (float*)d_out;
  unsigned long long* cs = (unsigned long long*)d_ws;  // 8192 packed {ready|sum}

  k0_init<<<NWAVE / TPB, TPB, 0, stream>>>(cs);
  k_scan<<<NBLK, TPB, 0, stream>>>(
      x_scaled, process_c, raw, lb, ub, sc, mat_idx, cs, out);
}

// Round 7
// 171.774 us; speedup vs baseline: 2.9271x; 1.0093x over previous
//
#include <hip/hip_runtime.h>

#define N_DATA   128
#define SEG_LEN  131072
#define NPROD    (SEG_LEN - 1)
#define N_MAT    8
#define N_MATP   8
#define N_PROCP  5
#define RGAS     8.314f

#define TPB      256
#define RUNS     8                     // runs of 4 elements per lane
#define WCHUNK   (64 * RUNS * 4)       // 2048 elements per wave-chunk
#define SPR      (SEG_LEN / WCHUNK)    // 64 slots per row
#define NITER    4                     // rows processed per persistent wave
#define RPI      (N_DATA / NITER)      // 32 rows per iteration
#define NWAVEP   (RPI * SPR)           // 2048 persistent waves
#define NBLK     (NWAVEP / (TPB / 64)) // 512 blocks = 2/CU: ALL co-resident
#define NSLOT    (N_DATA * SPR)        // 8192 packed {ready|sum} slots

typedef float nt4 __attribute__((ext_vector_type(4)));  // native vec for nontemporal builtin

// K0: re-arm the packed {ready|value} words (workspace is re-poisoned between
// iterations; poison bits could fake "ready"). Kernel => graph-capture-safe.
__global__ __launch_bounds__(TPB) void k0_init(unsigned long long* __restrict__ cs) {
  cs[blockIdx.x * TPB + threadIdx.x] = 0ull;
}

__device__ __forceinline__ void load_tile(const float* __restrict__ x,
    long rowbase, int gb0, int lane, float4 v[RUNS], float& xe) {
  const float* xb = x + rowbase + gb0;
  const float* xp = xb + lane * 4;
#pragma unroll
  for (int r = 0; r < RUNS; r++) v[r] = *(const float4*)(xp + r * 256);
  xe = 0.0f;                                   // cross-chunk edge (lane 63)
  if (lane == 63 && gb0 + WCHUNK < SEG_LEN) xe = xb[WCHUNK];
}

// Prefetch raw param words (sigmoid computed at use time). Lanes 0..12 fetch
// raw/lb/ub for the 13 row params; lanes 13..15 fetch R,T,P from process_c.
__device__ __forceinline__ void load_par(int row, int lane,
    const float* __restrict__ raw, const float* __restrict__ lb,
    const float* __restrict__ ub, const float* __restrict__ pc,
    const int* __restrict__ mat_idx, float& pr, float& pl, float& pu) {
  pr = 0.0f; pl = 0.0f; pu = 0.0f;
  if (lane < 13) {
    int idx = (lane < 5) ? (N_MAT * N_MATP + row * N_PROCP + lane)
                         : (mat_idx[row] * N_MATP + (lane - 5));
    pr = raw[idx]; pl = lb[idx]; pu = ub[idx];
  } else if (lane < 16) {
    pr = pc[row * 4 + (lane - 13)];
  }
}

// One pipelined iteration. Order is the whole point:
//   compute -> PUBLISH -> PREFETCH next row's loads -> scans/prep -> POLL ->
//   NT-store. Loads of iter k+1 are in flight across poll k and store k, so
//   the write drain + sync latency of iter k overlap the read ramp of k+1.
// Round-3 rule: every __shfl in FULL exec (only loads/selects divergent).
// Round-5 rule: flag+value in ONE u64, relaxed agent atomics, NO fences.
#define BODY(KK, VC, XEC, PRC, PLC, PUC, VN, XEN, PRN, PLN, PUN)             \
  {                                                                          \
    const int row = rb + RPI * (KK);                                         \
    const long rowbase = (long)row * SEG_LEN;                                \
    float pvl;                                                               \
    if (lane < 13) {                                                         \
      float sg = 1.0f / (1.0f + __expf(-(PRC)));                             \
      pvl = sg * ((PUC) - (PLC)) + (PLC);                                    \
    } else {                                                                 \
      pvl = (PRC);                                                           \
    }                                                                        \
    float SigmaC = __shfl(pvl, 0),  Kzero = __shfl(pvl, 1);                  \
    float alpha1 = __shfl(pvl, 2),  L0     = __shfl(pvl, 3);                 \
    float G200   = __shfl(pvl, 4),  Sigma0 = __shfl(pvl, 5);                 \
    float BetaD  = __shfl(pvl, 6),  Ea     = __shfl(pvl, 7);                 \
    float Mfda   = __shfl(pvl, 8),  Di     = __shfl(pvl, 9);                 \
    float A0     = __shfl(pvl, 10), B0     = __shfl(pvl, 11);                \
    float l0     = __shfl(pvl, 12);                                          \
    float R = __shfl(pvl, 13), T = __shfl(pvl, 14), P = __shfl(pvl, 15);     \
    float cbd      = BetaD * Di * __expf(-Ea / (RGAS * T));                  \
    float s0cbd    = Sigma0 * cbd;                                           \
    float base_num = SigmaC - Mfda * P;                                      \
    float inv_tau  = 1.0f / (B0 * l0 + 1e-9f);                               \
    float t[RUNS][4];                                                        \
    _Pragma("unroll")                                                        \
    for (int r = 0; r < RUNS; r++) {                                         \
      t[r][0] = VC[r].x * x_sc + x_min;                                      \
      t[r][1] = VC[r].y * x_sc + x_min;                                      \
      t[r][2] = VC[r].z * x_sc + x_min;                                      \
      t[r][3] = VC[r].w * x_sc + x_min;                                      \
    }                                                                        \
    float nx[RUNS];                                                          \
    {                                                                        \
      float dsh[RUNS], bcx[RUNS];                                            \
      _Pragma("unroll")                                                      \
      for (int r = 0; r < RUNS; r++) dsh[r] = __shfl_down(t[r][0], 1);       \
      _Pragma("unroll")                                                      \
      for (int r = 0; r < RUNS - 1; r++) bcx[r] = __shfl(t[r + 1][0], 0);    \
      bcx[RUNS - 1] = (XEC) * x_sc + x_min;   /* valid on lane 63 (only user) */ \
      bool lastl = (lane == 63);                                             \
      _Pragma("unroll")                                                      \
      for (int r = 0; r < RUNS; r++) nx[r] = lastl ? bcx[r] : dsh[r];        \
    }                                                                        \
    int glb = gb0 + lane * 4;                                                \
    float rs[RUNS];                                                          \
    _Pragma("unroll")                                                        \
    for (int r = 0; r < RUNS; r++) {                                         \
      float acc = 0.0f;                                                      \
      _Pragma("unroll")                                                      \
      for (int kq = 0; kq < 4; kq++) {                                       \
        float tn = (kq < 3) ? t[r][kq + 1] : nx[r];                          \
        float pp = 0.0f;                                                     \
        if (glb + r * 256 + kq < NPROD) {                                    \
          float Lg = G200 * __expf(alpha1 *                                  \
                       __logf(t[r][kq] * (1.0f / 200.0f) + 0.001f)) + L0;    \
          float u  = R * Lg + 1e-9f;                                         \
          float num = base_num * u * Lg + s0cbd;                             \
          float den = Lg * (u + cbd);                                        \
          float ss = num * __builtin_amdgcn_rcpf(den)                        \
                   + A0 * __expf(-t[r][kq] * inv_tau);                       \
          pp = ss * (tn - t[r][kq]);                                         \
        }                                                                    \
        acc += pp;                                                           \
        t[r][kq] = pp;        /* t now holds products */                     \
      }                                                                      \
      rs[r] = acc;                                                           \
    }                                                                        \
    float tot = rs[0]+rs[1]+rs[2]+rs[3]+rs[4]+rs[5]+rs[6]+rs[7];             \
    _Pragma("unroll")                                                        \
    for (int d = 1; d < 64; d <<= 1) tot += __shfl_xor(tot, d);              \
    if (lane == 0) {                                                         \
      unsigned long long u = (1ull << 32) |                                  \
          (unsigned long long)__float_as_uint(tot);                          \
      __hip_atomic_store(cs + ((row << 6) + s), u,                           \
                         __ATOMIC_RELAXED, __HIP_MEMORY_SCOPE_AGENT);        \
    }                                                                        \
    if ((KK) + 1 < NITER) {   /* prefetch next row BEFORE poll/store */      \
      load_par(rb + RPI * ((KK) + 1), lane, raw, lb, ub, pc, mat_idx,        \
               PRN, PLN, PUN);                                               \
      load_tile(x, (long)(rb + RPI * ((KK) + 1)) * SEG_LEN, gb0, lane,       \
                VN, XEN);                                                    \
    }                                                                        \
    float e[RUNS];                                                           \
    float carry = 0.0f;                                                      \
    _Pragma("unroll")                                                        \
    for (int r = 0; r < RUNS; r++) {                                         \
      float inc = rs[r];                                                     \
      _Pragma("unroll")                                                      \
      for (int d = 1; d < 64; d <<= 1) {                                     \
        float nn = __shfl_up(inc, d);                                        \
        if (lane >= d) inc += nn;                                            \
      }                                                                      \
      e[r] = carry + inc - rs[r];                                            \
      carry += __shfl(inc, 63);                                              \
    }                                                                        \
    _Pragma("unroll")                                                        \
    for (int r = 0; r < RUNS; r++) {                                         \
      float c0 = Kzero + e[r] - y_min;                                       \
      float c1 = c0 + t[r][0];                                               \
      float c2 = c1 + t[r][1];                                               \
      float c3 = c2 + t[r][2];                                               \
      t[r][0] = c0 * inv_yr; t[r][1] = c1 * inv_yr;                          \
      t[r][2] = c2 * inv_yr; t[r][3] = c3 * inv_yr;                          \
    }                                                                        \
    float vv = 0.0f;                                                         \
    if (lane < s) {           /* <=1 slot per lane; loads only, no shfl */   \
      const unsigned long long* p = cs + ((row << 6) + lane);                \
      unsigned long long u = __hip_atomic_load(p, __ATOMIC_RELAXED,          \
                                               __HIP_MEMORY_SCOPE_AGENT);    \
      while (!(unsigned)(u >> 32)) {                                         \
        __builtin_amdgcn_s_sleep(1);                                         \
        u = __hip_atomic_load(p, __ATOMIC_RELAXED,                           \
                              __HIP_MEMORY_SCOPE_AGENT);                     \
      }                                                                      \
      vv = __uint_as_float((unsigned)u);                                     \
    }                                                                        \
    _Pragma("unroll")                                                        \
    for (int d = 32; d > 0; d >>= 1) vv += __shfl_down(vv, d);  /* full exec */ \
    float choff = __shfl(vv, 0) * inv_yr;     /* already output-scaled */    \
    float* ob = out + rowbase + gb0 + lane * 4;                              \
    _Pragma("unroll")                                                        \
    for (int r = 0; r < RUNS; r++) {                                         \
      nt4 o;                                                                 \
      o.x = t[r][0] + choff; o.y = t[r][1] + choff;                          \
      o.z = t[r][2] + choff; o.w = t[r][3] + choff;                          \
      __builtin_nontemporal_store(o, (nt4*)(ob + r * 256));                  \
    }                                                                        \
  }

// Persistent-wave pipelined scan: 2048 waves (512 blocks, 2/CU -- ALL
// co-resident by construction), each handling slot s of rows rb+32k,
// k=0..3. Zero barriers, zero LDS, lane-dense 1024B loads/stores,
// fence-free packed-u64 sync. Iteration boundaries overlap write-drain and
// poll-wait of row k with the load ramp of row k+1 (loads issued pre-poll;
// vmcnt is in-issue-order so compute k+1 waits only for its own loads).
// NOTE: OccupancyPercent will read ~6-8% -- intentional (persistent waves).
__global__ __launch_bounds__(TPB) void k_scan(
    const float* __restrict__ x,
    const float* __restrict__ pc, const float* __restrict__ raw,
    const float* __restrict__ lb, const float* __restrict__ ub,
    const float* __restrict__ sc, const int* __restrict__ mat_idx,
    unsigned long long* __restrict__ cs,
    float* __restrict__ out) {
  int tid  = threadIdx.x;
  int lane = tid & 63;
  int W    = blockIdx.x * (TPB >> 6) + (tid >> 6);     // persistent wave id
  int rb   = __builtin_amdgcn_readfirstlane(W >> 6);   // base row 0..31
  int s    = __builtin_amdgcn_readfirstlane(W & (SPR - 1));
  int gb0  = s * WCHUNK;                               // row-local chunk base

  float x_min = sc[0], x_sc = sc[1] - sc[0];
  float y_min = sc[2], inv_yr = 1.0f / (sc[3] - sc[2]);

  // named double-buffers (rule: no runtime-indexed register arrays)
  float4 vA[RUNS], vB[RUNS];
  float xeA = 0.0f, xeB = 0.0f;
  float prA, plA, puA, prB, plB, puB;

  load_par(rb, lane, raw, lb, ub, pc, mat_idx, prA, plA, puA);
  load_tile(x, (long)rb * SEG_LEN, gb0, lane, vA, xeA);

  BODY(0, vA, xeA, prA, plA, puA, vB, xeB, prB, plB, puB)
  BODY(1, vB, xeB, prB, plB, puB, vA, xeA, prA, plA, puA)
  BODY(2, vA, xeA, prA, plA, puA, vB, xeB, prB, plB, puB)
  BODY(3, vB, xeB, prB, plB, puB, vA, xeA, prA, plA, puA)
}

extern "C" void kernel_launch(void* const* d_in, const int* in_sizes, int n_in,
                              void* d_out, int out_size, void* d_ws, size_t ws_size,
                              hipStream_t stream) {
  const float* x_scaled  = (const float*)d_in[0];
  const float* process_c = (const float*)d_in[1];
  const float* raw       = (const float*)d_in[2];
  const float* lb        = (const float*)d_in[3];
  const float* ub        = (const float*)d_in[4];
  const float* sc        = (const float*)d_in[5];
  // d_in[6] = fit_index (unused by the reference computation)
  const int*   mat_idx   = (const int*)d_in[7];
  float* out = (float*)d_out;
  unsigned long long* cs = (unsigned long long*)d_ws;  // 8192 packed {ready|sum}

  k0_init<<<NSLOT / TPB, TPB, 0, stream>>>(cs);
  k_scan<<<NBLK, TPB, 0, stream>>>(
      x_scaled, process_c, raw, lb, ub, sc, mat_idx, cs, out);
}